// Round 1
// baseline (1527.377 us; speedup 1.0000x reference)
//
#include <hip/hip_runtime.h>

#define N_NODES 100000
#define N_EDGES 1600000
#define D 128
#define DE 32
#define EPSF 1e-10f

// ---------------------------------------------------------------------------
// K1: zero accumulator (d_out), g, wsum; degrees start at 1.0 (the "+1").
__global__ __launch_bounds__(256) void init_kernel(
    float* __restrict__ acc, float* __restrict__ deg_in,
    float* __restrict__ deg_out, float* __restrict__ wsum,
    float* __restrict__ g) {
  int idx = blockIdx.x * 256 + threadIdx.x;
  if (idx < N_NODES * D) acc[idx] = 0.f;
  if (idx < N_NODES * DE) g[idx] = 0.f;
  if (idx < N_NODES) {
    deg_in[idx] = 1.f;
    deg_out[idx] = 1.f;
    wsum[idx] = 0.f;
  }
}

// ---------------------------------------------------------------------------
// K2: weighted degree histograms.
__global__ __launch_bounds__(256) void deg_kernel(
    const int* __restrict__ el, const float* __restrict__ ew,
    float* __restrict__ deg_in, float* __restrict__ deg_out) {
  int i = blockIdx.x * 256 + threadIdx.x;
  if (i >= N_EDGES) return;
  int src = el[2 * i];
  int dst = el[2 * i + 1];
  float w = ew[i];
  atomicAdd(&deg_in[src], w);
  atomicAdd(&deg_out[dst], w);
}

// ---------------------------------------------------------------------------
// K3: one wave (64 lanes) per edge.
//   acc[dst] += w * x[src]          (128 dwords, lanes cover d = lane, lane+64)
//   g[dst]   += w * ef[e]           (32 dwords, lanes 0..31)
//   wsum[dst]+= w                   (lane 63)
__global__ __launch_bounds__(256) void scatter_kernel(
    const int* __restrict__ el, const float* __restrict__ ew,
    const float* __restrict__ ef, const float* __restrict__ x,
    const float* __restrict__ deg_in, const float* __restrict__ deg_out,
    float* __restrict__ acc, float* __restrict__ g,
    float* __restrict__ wsum) {
  long long gid = (long long)blockIdx.x * 256 + threadIdx.x;
  int e = (int)(gid >> 6);
  int lane = (int)(gid & 63);
  if (e >= N_EDGES) return;
  int src = el[2 * e];
  int dst = el[2 * e + 1];
  float w = ew[e] / (sqrtf(deg_in[src] * deg_out[dst]) + EPSF);
  const float* xs = x + (size_t)src * D;
  float* ad = acc + (size_t)dst * D;
  atomicAdd(&ad[lane], w * xs[lane]);
  atomicAdd(&ad[lane + 64], w * xs[lane + 64]);
  if (lane < DE) {
    atomicAdd(&g[dst * DE + lane], w * ef[(size_t)e * DE + lane]);
  } else if (lane == 63) {
    atomicAdd(&wsum[dst], w);
  }
}

// ---------------------------------------------------------------------------
// K4: per 64-node block:
//   upd[v] = acc[v] + wself*x[v] + g[v] @ W_edge^T + wsum[v]*b_edge   (LDS)
//   out[v] = relu(upd[v] @ W_lin^T + b_lin)                           (in place)
// LDS stride 129 -> bank-conflict-free for both phases.
// Phase B: each wave owns 32 output dims -> W_lin row address is wave-uniform
// (single broadcast transaction), LDS read lanes vary node -> conflict-free.
__global__ __launch_bounds__(256) void final_kernel(
    const float* __restrict__ x, const float* __restrict__ deg_in,
    const float* __restrict__ deg_out, const float* __restrict__ wsum,
    const float* __restrict__ g, const float* __restrict__ W_lin,
    const float* __restrict__ b_lin, const float* __restrict__ W_edge,
    const float* __restrict__ b_edge, float* __restrict__ acc) {
  __shared__ float upd[64 * 129];
  int nodeBase = blockIdx.x * 64;

  // Phase A: build update rows.
  for (int idx = threadIdx.x; idx < 64 * D; idx += 256) {
    int vl = idx >> 7;
    int d = idx & 127;
    int v = nodeBase + vl;
    float val = 0.f;
    if (v < N_NODES) {
      float ws = wsum[v];
      float wself = 1.f / (sqrtf(deg_in[v] * deg_out[v]) + EPSF);
      size_t o = (size_t)v * D + d;
      val = acc[o] + wself * x[o] + ws * b_edge[d];
      const float* gv = g + v * DE;
      const float* we = W_edge + d * DE;
      float s = 0.f;
#pragma unroll
      for (int k = 0; k < DE; k++) s += gv[k] * we[k];
      val += s;
    }
    upd[vl * 129 + d] = val;
  }
  __syncthreads();

  // Phase B: out = relu(upd @ W_lin^T + b_lin), written in place.
  int vl = threadIdx.x & 63;
  int wv = threadIdx.x >> 6;
  int v = nodeBase + vl;
  if (v >= N_NODES) return;
  const float* urow = &upd[vl * 129];
  for (int j0 = wv * 32; j0 < wv * 32 + 32; j0 += 4) {
    const float* w0 = W_lin + (size_t)j0 * D;
    float s0 = b_lin[j0], s1 = b_lin[j0 + 1];
    float s2 = b_lin[j0 + 2], s3 = b_lin[j0 + 3];
    for (int k = 0; k < D; k++) {
      float u = urow[k];
      s0 += u * w0[k];
      s1 += u * w0[D + k];
      s2 += u * w0[2 * D + k];
      s3 += u * w0[3 * D + k];
    }
    float4 r;
    r.x = fmaxf(s0, 0.f);
    r.y = fmaxf(s1, 0.f);
    r.z = fmaxf(s2, 0.f);
    r.w = fmaxf(s3, 0.f);
    *(float4*)(acc + (size_t)v * D + j0) = r;
  }
}

// ---------------------------------------------------------------------------
extern "C" void kernel_launch(void* const* d_in, const int* in_sizes, int n_in,
                              void* d_out, int out_size, void* d_ws,
                              size_t ws_size, hipStream_t stream) {
  const float* x      = (const float*)d_in[0];
  const int*   el     = (const int*)d_in[1];
  const float* ew     = (const float*)d_in[2];
  const float* ef     = (const float*)d_in[3];
  const float* W_lin  = (const float*)d_in[4];
  const float* b_lin  = (const float*)d_in[5];
  const float* W_edge = (const float*)d_in[6];
  const float* b_edge = (const float*)d_in[7];

  float* acc = (float*)d_out;  // N_NODES x 128 accumulator, finalized in place

  // workspace: deg_in[N] | deg_out[N] | wsum[N] | g[N*32]  (= 14 MB)
  float* deg_in = (float*)d_ws;
  float* deg_out = deg_in + N_NODES;
  float* wsum = deg_out + N_NODES;
  float* g = wsum + N_NODES;

  hipLaunchKernelGGL(init_kernel, dim3((N_NODES * D + 255) / 256), dim3(256), 0,
                     stream, acc, deg_in, deg_out, wsum, g);
  hipLaunchKernelGGL(deg_kernel, dim3((N_EDGES + 255) / 256), dim3(256), 0,
                     stream, el, ew, deg_in, deg_out);
  hipLaunchKernelGGL(scatter_kernel, dim3(N_EDGES / 4), dim3(256), 0, stream,
                     el, ew, ef, x, deg_in, deg_out, acc, g, wsum);
  hipLaunchKernelGGL(final_kernel, dim3((N_NODES + 63) / 64), dim3(256), 0,
                     stream, x, deg_in, deg_out, wsum, g, W_lin, b_lin, W_edge,
                     b_edge, acc);
}

// Round 2
// 959.303 us; speedup vs baseline: 1.5922x; 1.5922x over previous
//
#include <hip/hip_runtime.h>

#define N_NODES 100000
#define N_EDGES 1600000
#define D 128
#define DE 32
#define EPSF 1e-10f
#define SCAN_CHUNK 1024
#define N_CHUNKS ((N_NODES + SCAN_CHUNK - 1) / SCAN_CHUNK)  // 98

// ---------------------------------------------------------------------------
// K1: degrees start at 1.0 (the "+1"); zero CSR counters.
__global__ __launch_bounds__(256) void init_kernel(
    float* __restrict__ deg_in, float* __restrict__ deg_out,
    int* __restrict__ counts, int* __restrict__ cursor) {
  int idx = blockIdx.x * 256 + threadIdx.x;
  if (idx < N_NODES) {
    deg_in[idx] = 1.f;
    deg_out[idx] = 1.f;
    counts[idx] = 0;
    cursor[idx] = 0;
  }
}

// ---------------------------------------------------------------------------
// K2: weighted degree histograms + per-dst edge counts.
__global__ __launch_bounds__(256) void deg_kernel(
    const int* __restrict__ el, const float* __restrict__ ew,
    float* __restrict__ deg_in, float* __restrict__ deg_out,
    int* __restrict__ counts) {
  int i = blockIdx.x * 256 + threadIdx.x;
  if (i >= N_EDGES) return;
  int src = el[2 * i];
  int dst = el[2 * i + 1];
  float w = ew[i];
  atomicAdd(&deg_in[src], w);
  atomicAdd(&deg_out[dst], w);
  atomicAdd(&counts[dst], 1);
}

// ---------------------------------------------------------------------------
// K3a: per-1024-chunk exclusive scan of counts -> partial, chunk totals.
__global__ __launch_bounds__(256) void scan1_kernel(
    const int* __restrict__ counts, int* __restrict__ partial,
    int* __restrict__ blocksum) {
  __shared__ int lds[256];
  int t = threadIdx.x;
  int base = blockIdx.x * SCAN_CHUNK + t * 4;
  int c[4];
  int s = 0;
#pragma unroll
  for (int k = 0; k < 4; k++) {
    c[k] = (base + k < N_NODES) ? counts[base + k] : 0;
    s += c[k];
  }
  lds[t] = s;
  __syncthreads();
  for (int off = 1; off < 256; off <<= 1) {
    int tmp = (t >= off) ? lds[t - off] : 0;
    __syncthreads();
    lds[t] += tmp;
    __syncthreads();
  }
  int run = lds[t] - s;  // exclusive prefix of this thread's 4-group
#pragma unroll
  for (int k = 0; k < 4; k++) {
    if (base + k < N_NODES) partial[base + k] = run;
    run += c[k];
  }
  if (t == 255) blocksum[blockIdx.x] = lds[255];
}

// ---------------------------------------------------------------------------
// K3b: exclusive scan of the 98 chunk totals.
__global__ __launch_bounds__(128) void scan2_kernel(
    const int* __restrict__ blocksum, int* __restrict__ blockoff) {
  __shared__ int lds[128];
  int t = threadIdx.x;
  int v = (t < N_CHUNKS) ? blocksum[t] : 0;
  lds[t] = v;
  __syncthreads();
  for (int off = 1; off < 128; off <<= 1) {
    int tmp = (t >= off) ? lds[t - off] : 0;
    __syncthreads();
    lds[t] += tmp;
    __syncthreads();
  }
  if (t < N_CHUNKS) blockoff[t] = lds[t] - v;
}

// ---------------------------------------------------------------------------
// K4: place (src, w, edge_id) into CSR slots ordered by dst.
__global__ __launch_bounds__(256) void fill_kernel(
    const int* __restrict__ el, const float* __restrict__ ew,
    const float* __restrict__ deg_in, const float* __restrict__ deg_out,
    const int* __restrict__ partial, const int* __restrict__ blockoff,
    int* __restrict__ cursor, int* __restrict__ edge_src,
    float* __restrict__ edge_w, int* __restrict__ edge_eid) {
  int i = blockIdx.x * 256 + threadIdx.x;
  if (i >= N_EDGES) return;
  int src = el[2 * i];
  int dst = el[2 * i + 1];
  float w = ew[i] / (sqrtf(deg_in[src] * deg_out[dst]) + EPSF);
  int pos = partial[dst] + blockoff[dst >> 10] + atomicAdd(&cursor[dst], 1);
  edge_src[pos] = src;
  edge_w[pos] = w;
  edge_eid[pos] = i;
}

// ---------------------------------------------------------------------------
// K5: one wave per dst node. Batch-load 64 edges coalesced, shfl-broadcast,
// accumulate sum(w*x[src]) (2 regs/lane), sum(w*ef) (lanes 0..31), sum(w).
// Plain stores — no atomics.
__global__ __launch_bounds__(256) void gather_kernel(
    const float* __restrict__ x, const float* __restrict__ ef,
    const int* __restrict__ partial, const int* __restrict__ blockoff,
    const int* __restrict__ counts, const int* __restrict__ edge_src,
    const float* __restrict__ edge_w, const int* __restrict__ edge_eid,
    float* __restrict__ acc, float* __restrict__ g,
    float* __restrict__ wsum) {
  int wid = threadIdx.x >> 6;
  int lane = threadIdx.x & 63;
  int v = blockIdx.x * 4 + wid;
  if (v >= N_NODES) return;
  int start = partial[v] + blockoff[v >> 10];
  int cnt = counts[v];
  float a0 = 0.f, a1 = 0.f, ga = 0.f, wsv = 0.f;
  for (int base = 0; base < cnt; base += 64) {
    int nb = cnt - base;
    if (nb > 64) nb = 64;
    int s_l = 0, e_l = 0;
    float w_l = 0.f;
    if (lane < nb) {
      int p = start + base + lane;
      s_l = edge_src[p];
      w_l = edge_w[p];
      e_l = edge_eid[p];
    }
    for (int i = 0; i < nb; i++) {
      int s = __shfl(s_l, i);
      float w = __shfl(w_l, i);
      int eid = __shfl(e_l, i);
      const float* xs = x + (size_t)s * D;
      a0 = fmaf(w, xs[lane], a0);
      a1 = fmaf(w, xs[lane + 64], a1);
      if (lane < DE) ga = fmaf(w, ef[(size_t)eid * DE + lane], ga);
      wsv += w;
    }
  }
  float* ad = acc + (size_t)v * D;
  ad[lane] = a0;
  ad[lane + 64] = a1;
  if (lane < DE) g[v * DE + lane] = ga;
  if (lane == 0) wsum[v] = wsv;
}

// ---------------------------------------------------------------------------
// K6: per 64-node block:
//   upd[v] = acc[v] + wself*x[v] + g[v] @ W_edge^T + wsum[v]*b_edge   (LDS)
//   out[v] = relu(upd[v] @ W_lin^T + b_lin)                           (in place)
__global__ __launch_bounds__(256) void final_kernel(
    const float* __restrict__ x, const float* __restrict__ deg_in,
    const float* __restrict__ deg_out, const float* __restrict__ wsum,
    const float* __restrict__ g, const float* __restrict__ W_lin,
    const float* __restrict__ b_lin, const float* __restrict__ W_edge,
    const float* __restrict__ b_edge, float* __restrict__ acc) {
  __shared__ float upd[64 * 129];
  int nodeBase = blockIdx.x * 64;

  for (int idx = threadIdx.x; idx < 64 * D; idx += 256) {
    int vl = idx >> 7;
    int d = idx & 127;
    int v = nodeBase + vl;
    float val = 0.f;
    if (v < N_NODES) {
      float ws = wsum[v];
      float wself = 1.f / (sqrtf(deg_in[v] * deg_out[v]) + EPSF);
      size_t o = (size_t)v * D + d;
      val = acc[o] + wself * x[o] + ws * b_edge[d];
      const float* gv = g + v * DE;
      const float* we = W_edge + d * DE;
      float s = 0.f;
#pragma unroll
      for (int k = 0; k < DE; k++) s += gv[k] * we[k];
      val += s;
    }
    upd[vl * 129 + d] = val;
  }
  __syncthreads();

  int vl = threadIdx.x & 63;
  int wv = threadIdx.x >> 6;
  int v = nodeBase + vl;
  if (v >= N_NODES) return;
  const float* urow = &upd[vl * 129];
  for (int j0 = wv * 32; j0 < wv * 32 + 32; j0 += 4) {
    const float* w0 = W_lin + (size_t)j0 * D;
    float s0 = b_lin[j0], s1 = b_lin[j0 + 1];
    float s2 = b_lin[j0 + 2], s3 = b_lin[j0 + 3];
    for (int k = 0; k < D; k++) {
      float u = urow[k];
      s0 += u * w0[k];
      s1 += u * w0[D + k];
      s2 += u * w0[2 * D + k];
      s3 += u * w0[3 * D + k];
    }
    float4 r;
    r.x = fmaxf(s0, 0.f);
    r.y = fmaxf(s1, 0.f);
    r.z = fmaxf(s2, 0.f);
    r.w = fmaxf(s3, 0.f);
    *(float4*)(acc + (size_t)v * D + j0) = r;
  }
}

// ---------------------------------------------------------------------------
extern "C" void kernel_launch(void* const* d_in, const int* in_sizes, int n_in,
                              void* d_out, int out_size, void* d_ws,
                              size_t ws_size, hipStream_t stream) {
  const float* x      = (const float*)d_in[0];
  const int*   el     = (const int*)d_in[1];
  const float* ew     = (const float*)d_in[2];
  const float* ef     = (const float*)d_in[3];
  const float* W_lin  = (const float*)d_in[4];
  const float* b_lin  = (const float*)d_in[5];
  const float* W_edge = (const float*)d_in[6];
  const float* b_edge = (const float*)d_in[7];

  float* acc = (float*)d_out;  // gather writes, final reads + writes in place

  // workspace layout (~34.4 MB)
  float* deg_in  = (float*)d_ws;                    // N
  float* deg_out = deg_in + N_NODES;                // N
  float* wsum    = deg_out + N_NODES;               // N
  float* g       = wsum + N_NODES;                  // N*32
  int* counts    = (int*)(g + (size_t)N_NODES * DE);// N
  int* partial   = counts + N_NODES;                // N
  int* blocksum  = partial + N_NODES;               // 128
  int* blockoff  = blocksum + 128;                  // 128
  int* cursor    = blockoff + 128;                  // N
  int* edge_src  = cursor + N_NODES;                // E
  int* edge_eid  = edge_src + N_EDGES;              // E
  float* edge_w  = (float*)(edge_eid + N_EDGES);    // E

  hipLaunchKernelGGL(init_kernel, dim3((N_NODES + 255) / 256), dim3(256), 0,
                     stream, deg_in, deg_out, counts, cursor);
  hipLaunchKernelGGL(deg_kernel, dim3((N_EDGES + 255) / 256), dim3(256), 0,
                     stream, el, ew, deg_in, deg_out, counts);
  hipLaunchKernelGGL(scan1_kernel, dim3(N_CHUNKS), dim3(256), 0, stream,
                     counts, partial, blocksum);
  hipLaunchKernelGGL(scan2_kernel, dim3(1), dim3(128), 0, stream, blocksum,
                     blockoff);
  hipLaunchKernelGGL(fill_kernel, dim3((N_EDGES + 255) / 256), dim3(256), 0,
                     stream, el, ew, deg_in, deg_out, partial, blockoff, cursor,
                     edge_src, edge_w, edge_eid);
  hipLaunchKernelGGL(gather_kernel, dim3((N_NODES + 3) / 4), dim3(256), 0,
                     stream, x, ef, partial, blockoff, counts, edge_src, edge_w,
                     edge_eid, acc, g, wsum);
  hipLaunchKernelGGL(final_kernel, dim3((N_NODES + 63) / 64), dim3(256), 0,
                     stream, x, deg_in, deg_out, wsum, g, W_lin, b_lin, W_edge,
                     b_edge, acc);
}

// Round 3
// 633.426 us; speedup vs baseline: 2.4113x; 1.5145x over previous
//
#include <hip/hip_runtime.h>

#define N_NODES 100000
#define N_EDGES 1600000
#define D 128
#define DE 32
#define EPSF 1e-10f
#define SCAN_CHUNK 1024
#define N_CHUNKS ((N_NODES + SCAN_CHUNK - 1) / SCAN_CHUNK)  // 98

// ---------------------------------------------------------------------------
// K1: degrees start at 1.0 (the "+1"); zero CSR counters.
__global__ __launch_bounds__(256) void init_kernel(
    float* __restrict__ deg_in, float* __restrict__ deg_out,
    int* __restrict__ counts, int* __restrict__ cursor) {
  int idx = blockIdx.x * 256 + threadIdx.x;
  if (idx < N_NODES) {
    deg_in[idx] = 1.f;
    deg_out[idx] = 1.f;
    counts[idx] = 0;
    cursor[idx] = 0;
  }
}

// ---------------------------------------------------------------------------
// K2: weighted degree histograms + per-dst edge counts. 2 edges/thread.
__global__ __launch_bounds__(256) void deg_kernel(
    const int4* __restrict__ el2, const float2* __restrict__ ew2,
    float* __restrict__ deg_in, float* __restrict__ deg_out,
    int* __restrict__ counts) {
  int i = blockIdx.x * 256 + threadIdx.x;  // edge-pair index
  if (i >= N_EDGES / 2) return;
  int4 e = el2[i];
  float2 w = ew2[i];
  atomicAdd(&deg_in[e.x], w.x);
  atomicAdd(&deg_out[e.y], w.x);
  atomicAdd(&counts[e.y], 1);
  atomicAdd(&deg_in[e.z], w.y);
  atomicAdd(&deg_out[e.w], w.y);
  atomicAdd(&counts[e.w], 1);
}

// ---------------------------------------------------------------------------
// K3a: per-1024-chunk exclusive scan of counts -> partial, chunk totals.
__global__ __launch_bounds__(256) void scan1_kernel(
    const int* __restrict__ counts, int* __restrict__ partial,
    int* __restrict__ blocksum) {
  __shared__ int lds[256];
  int t = threadIdx.x;
  int base = blockIdx.x * SCAN_CHUNK + t * 4;
  int c[4];
  int s = 0;
#pragma unroll
  for (int k = 0; k < 4; k++) {
    c[k] = (base + k < N_NODES) ? counts[base + k] : 0;
    s += c[k];
  }
  lds[t] = s;
  __syncthreads();
  for (int off = 1; off < 256; off <<= 1) {
    int tmp = (t >= off) ? lds[t - off] : 0;
    __syncthreads();
    lds[t] += tmp;
    __syncthreads();
  }
  int run = lds[t] - s;
#pragma unroll
  for (int k = 0; k < 4; k++) {
    if (base + k < N_NODES) partial[base + k] = run;
    run += c[k];
  }
  if (t == 255) blocksum[blockIdx.x] = lds[255];
}

// ---------------------------------------------------------------------------
// K3b: exclusive scan of the 98 chunk totals.
__global__ __launch_bounds__(128) void scan2_kernel(
    const int* __restrict__ blocksum, int* __restrict__ blockoff) {
  __shared__ int lds[128];
  int t = threadIdx.x;
  int v = (t < N_CHUNKS) ? blocksum[t] : 0;
  lds[t] = v;
  __syncthreads();
  for (int off = 1; off < 128; off <<= 1) {
    int tmp = (t >= off) ? lds[t - off] : 0;
    __syncthreads();
    lds[t] += tmp;
    __syncthreads();
  }
  if (t < N_CHUNKS) blockoff[t] = lds[t] - v;
}

// ---------------------------------------------------------------------------
// K4: place 16B AoS records {src, eid, w, 0} into CSR slots ordered by dst.
__global__ __launch_bounds__(256) void fill_kernel(
    const int* __restrict__ el, const float* __restrict__ ew,
    const float* __restrict__ deg_in, const float* __restrict__ deg_out,
    const int* __restrict__ partial, const int* __restrict__ blockoff,
    int* __restrict__ cursor, int4* __restrict__ rec) {
  int i = blockIdx.x * 256 + threadIdx.x;
  if (i >= N_EDGES) return;
  int src = el[2 * i];
  int dst = el[2 * i + 1];
  float w = ew[i] / (sqrtf(deg_in[src] * deg_out[dst]) + EPSF);
  int pos = partial[dst] + blockoff[dst >> 10] + atomicAdd(&cursor[dst], 1);
  int4 r;
  r.x = src;
  r.y = i;
  r.z = __float_as_int(w);
  r.w = 0;
  rec[pos] = r;
}

// ---------------------------------------------------------------------------
// K5: one wave per dst node; 2 edges per inner iteration (MLP x2),
// half-wave split for the 32-wide ef gather. Plain stores, no atomics.
__global__ __launch_bounds__(256) void gather_kernel(
    const float* __restrict__ x, const float* __restrict__ ef,
    const int* __restrict__ partial, const int* __restrict__ blockoff,
    const int* __restrict__ counts, const int4* __restrict__ rec,
    float* __restrict__ acc, float* __restrict__ g,
    float* __restrict__ wsum) {
  int wid = threadIdx.x >> 6;
  int lane = threadIdx.x & 63;
  int v = blockIdx.x * 4 + wid;
  if (v >= N_NODES) return;
  int start = partial[v] + blockoff[v >> 10];
  int cnt = counts[v];
  float a0 = 0.f, a1 = 0.f, b0 = 0.f, b1 = 0.f, ga = 0.f, wsv = 0.f;
  for (int base = 0; base < cnt; base += 64) {
    int nb = cnt - base;
    if (nb > 64) nb = 64;
    int s_l = 0, e_l = 0;
    float w_l = 0.f;
    if (lane < nb) {
      int4 r = rec[start + base + lane];
      s_l = r.x;
      e_l = r.y;
      w_l = __int_as_float(r.z);
    }
    int i = 0;
    for (; i + 2 <= nb; i += 2) {
      int sA = __shfl(s_l, i), sB = __shfl(s_l, i + 1);
      float wA = __shfl(w_l, i), wB = __shfl(w_l, i + 1);
      int eA = __shfl(e_l, i), eB = __shfl(e_l, i + 1);
      const float* xA = x + (size_t)sA * D;
      const float* xB = x + (size_t)sB * D;
      float xa0 = xA[lane], xa1 = xA[lane + 64];
      float xb0 = xB[lane], xb1 = xB[lane + 64];
      float we = (lane < 32) ? wA : wB;
      int ee = (lane < 32) ? eA : eB;
      float efv = ef[(size_t)ee * DE + (lane & 31)];
      a0 = fmaf(wA, xa0, a0);
      a1 = fmaf(wA, xa1, a1);
      b0 = fmaf(wB, xb0, b0);
      b1 = fmaf(wB, xb1, b1);
      ga = fmaf(we, efv, ga);
      wsv += wA + wB;
    }
    if (i < nb) {
      int sA = __shfl(s_l, i);
      float wA = __shfl(w_l, i);
      int eA = __shfl(e_l, i);
      const float* xA = x + (size_t)sA * D;
      a0 = fmaf(wA, xA[lane], a0);
      a1 = fmaf(wA, xA[lane + 64], a1);
      if (lane < DE) ga = fmaf(wA, ef[(size_t)eA * DE + lane], ga);
      wsv += wA;
    }
  }
  a0 += b0;
  a1 += b1;
  float gaHi = __shfl(ga, (lane + 32) & 63);
  float* ad = acc + (size_t)v * D;
  ad[lane] = a0;
  ad[lane + 64] = a1;
  if (lane < DE) g[v * DE + lane] = ga + gaHi;
  if (lane == 0) wsum[v] = wsv;
}

// ---------------------------------------------------------------------------
// K6: two-stage LDS GEMM per 64-node block.
//   GEMM1: upd = acc + wself*x + wsum*b_edge + g @ W_edge^T   (into LDS)
//   GEMM2: out = relu(upd @ W_lin^T + b_lin)                   (in place)
// Thread tile: 2 nodes x 4 cols; W tiles XOR-swizzled (col ^= 4*(row>>2))
// so staging writes are 2-way (free) and row-gather b128 reads hit 8
// distinct banks. acc/x/out global accesses are float4-coalesced.
__global__ __launch_bounds__(256) void final_kernel(
    const float* __restrict__ x, const float* __restrict__ deg_in,
    const float* __restrict__ deg_out, const float* __restrict__ wsum,
    const float* __restrict__ g, const float* __restrict__ W_lin,
    const float* __restrict__ b_lin, const float* __restrict__ W_edge,
    const float* __restrict__ b_edge, float* __restrict__ acc) {
  __shared__ float upd[64][132];    // 33792 B
  __shared__ float wtile[32][132];  // 16896 B (W_edge tiles, then W_lin tiles)
  __shared__ float g_lds[64][36];   //  9216 B
  __shared__ float wselfS[64], wsS[64];

  int t = threadIdx.x;
  int vbase = blockIdx.x * 64;
  int ti = t >> 3;  // 0..31 -> nodes 2ti, 2ti+1
  int tj = t & 7;   // 0..7  -> cols 4tj..4tj+3 within a 32-tile
  int swz = 4 * tj;

  // stage g rows + per-node scalars
  for (int idx = t; idx < 64 * DE; idx += 256) {
    int n = idx >> 5, k = idx & 31;
    int v = vbase + n;
    g_lds[n][k] = (v < N_NODES) ? g[v * DE + k] : 0.f;
  }
  if (t < 64) {
    int v = vbase + t;
    if (v < N_NODES) {
      wselfS[t] = 1.f / (sqrtf(deg_in[v] * deg_out[v]) + EPSF);
      wsS[t] = wsum[v];
    } else {
      wselfS[t] = 0.f;
      wsS[t] = 0.f;
    }
  }

  int n0 = 2 * ti, n1 = n0 + 1;
  bool ok0 = (vbase + n0) < N_NODES;
  bool ok1 = (vbase + n1) < N_NODES;

  // ---- GEMM1: 4 d-tiles of 32 ----
  for (int dt = 0; dt < 4; ++dt) {
    __syncthreads();  // wtile reuse; first iter also covers g/scalar staging
    for (int idx = t; idx < 32 * DE; idx += 256) {
      int dd = idx >> 5, k = idx & 31;
      wtile[dd][k ^ (4 * (dd >> 2))] = W_edge[(dt * 32 + dd) * DE + k];
    }
    __syncthreads();
    int dcol = dt * 32 + 4 * tj;
    float4 be = *(const float4*)&b_edge[dcol];
    float4 o0 = make_float4(0.f, 0.f, 0.f, 0.f), o1 = o0;
    if (ok0) {
      float4 a = *(const float4*)&acc[(size_t)(vbase + n0) * D + dcol];
      float4 xv = *(const float4*)&x[(size_t)(vbase + n0) * D + dcol];
      float wf = wselfS[n0], ws = wsS[n0];
      o0.x = a.x + wf * xv.x + ws * be.x;
      o0.y = a.y + wf * xv.y + ws * be.y;
      o0.z = a.z + wf * xv.z + ws * be.z;
      o0.w = a.w + wf * xv.w + ws * be.w;
    }
    if (ok1) {
      float4 a = *(const float4*)&acc[(size_t)(vbase + n1) * D + dcol];
      float4 xv = *(const float4*)&x[(size_t)(vbase + n1) * D + dcol];
      float wf = wselfS[n1], ws = wsS[n1];
      o1.x = a.x + wf * xv.x + ws * be.x;
      o1.y = a.y + wf * xv.y + ws * be.y;
      o1.z = a.z + wf * xv.z + ws * be.z;
      o1.w = a.w + wf * xv.w + ws * be.w;
    }
#pragma unroll
    for (int k0 = 0; k0 < DE; k0 += 4) {
      float4 u0 = *(const float4*)&g_lds[n0][k0];
      float4 u1 = *(const float4*)&g_lds[n1][k0];
      float4 w0 = *(const float4*)&wtile[4 * tj + 0][k0 ^ swz];
      float4 w1 = *(const float4*)&wtile[4 * tj + 1][k0 ^ swz];
      float4 w2 = *(const float4*)&wtile[4 * tj + 2][k0 ^ swz];
      float4 w3 = *(const float4*)&wtile[4 * tj + 3][k0 ^ swz];
      o0.x += u0.x * w0.x + u0.y * w0.y + u0.z * w0.z + u0.w * w0.w;
      o0.y += u0.x * w1.x + u0.y * w1.y + u0.z * w1.z + u0.w * w1.w;
      o0.z += u0.x * w2.x + u0.y * w2.y + u0.z * w2.z + u0.w * w2.w;
      o0.w += u0.x * w3.x + u0.y * w3.y + u0.z * w3.z + u0.w * w3.w;
      o1.x += u1.x * w0.x + u1.y * w0.y + u1.z * w0.z + u1.w * w0.w;
      o1.y += u1.x * w1.x + u1.y * w1.y + u1.z * w1.z + u1.w * w1.w;
      o1.z += u1.x * w2.x + u1.y * w2.y + u1.z * w2.z + u1.w * w2.w;
      o1.w += u1.x * w3.x + u1.y * w3.y + u1.z * w3.z + u1.w * w3.w;
    }
    *(float4*)&upd[n0][dcol] = o0;
    *(float4*)&upd[n1][dcol] = o1;
  }

  // ---- GEMM2: 4 j-tiles of 32 ----
  for (int jt = 0; jt < 4; ++jt) {
    __syncthreads();  // wtile reuse; first iter also covers upd completion
    for (int idx = t; idx < 32 * D; idx += 256) {
      int jj = idx >> 7, k = idx & 127;
      wtile[jj][k ^ (4 * (jj >> 2))] = W_lin[(jt * 32 + jj) * D + k];
    }
    __syncthreads();
    int jcol = jt * 32 + 4 * tj;
    float4 bl = *(const float4*)&b_lin[jcol];
    float4 o0 = bl, o1 = bl;
#pragma unroll 4
    for (int k0 = 0; k0 < D; k0 += 4) {
      float4 u0 = *(const float4*)&upd[n0][k0];
      float4 u1 = *(const float4*)&upd[n1][k0];
      float4 w0 = *(const float4*)&wtile[4 * tj + 0][k0 ^ swz];
      float4 w1 = *(const float4*)&wtile[4 * tj + 1][k0 ^ swz];
      float4 w2 = *(const float4*)&wtile[4 * tj + 2][k0 ^ swz];
      float4 w3 = *(const float4*)&wtile[4 * tj + 3][k0 ^ swz];
      o0.x += u0.x * w0.x + u0.y * w0.y + u0.z * w0.z + u0.w * w0.w;
      o0.y += u0.x * w1.x + u0.y * w1.y + u0.z * w1.z + u0.w * w1.w;
      o0.z += u0.x * w2.x + u0.y * w2.y + u0.z * w2.z + u0.w * w2.w;
      o0.w += u0.x * w3.x + u0.y * w3.y + u0.z * w3.z + u0.w * w3.w;
      o1.x += u1.x * w0.x + u1.y * w0.y + u1.z * w0.z + u1.w * w0.w;
      o1.y += u1.x * w1.x + u1.y * w1.y + u1.z * w1.z + u1.w * w1.w;
      o1.z += u1.x * w2.x + u1.y * w2.y + u1.z * w2.z + u1.w * w2.w;
      o1.w += u1.x * w3.x + u1.y * w3.y + u1.z * w3.z + u1.w * w3.w;
    }
    o0.x = fmaxf(o0.x, 0.f); o0.y = fmaxf(o0.y, 0.f);
    o0.z = fmaxf(o0.z, 0.f); o0.w = fmaxf(o0.w, 0.f);
    o1.x = fmaxf(o1.x, 0.f); o1.y = fmaxf(o1.y, 0.f);
    o1.z = fmaxf(o1.z, 0.f); o1.w = fmaxf(o1.w, 0.f);
    if (ok0) *(float4*)&acc[(size_t)(vbase + n0) * D + jcol] = o0;
    if (ok1) *(float4*)&acc[(size_t)(vbase + n1) * D + jcol] = o1;
  }
}

// ---------------------------------------------------------------------------
extern "C" void kernel_launch(void* const* d_in, const int* in_sizes, int n_in,
                              void* d_out, int out_size, void* d_ws,
                              size_t ws_size, hipStream_t stream) {
  const float* x      = (const float*)d_in[0];
  const int*   el     = (const int*)d_in[1];
  const float* ew     = (const float*)d_in[2];
  const float* ef     = (const float*)d_in[3];
  const float* W_lin  = (const float*)d_in[4];
  const float* b_lin  = (const float*)d_in[5];
  const float* W_edge = (const float*)d_in[6];
  const float* b_edge = (const float*)d_in[7];

  float* acc = (float*)d_out;  // gather writes, final reads + writes in place

  // workspace layout (~40.8 MB)
  float* deg_in  = (float*)d_ws;                     // N
  float* deg_out = deg_in + N_NODES;                 // N
  float* wsum    = deg_out + N_NODES;                // N
  float* g       = wsum + N_NODES;                   // N*32
  int* counts    = (int*)(g + (size_t)N_NODES * DE); // N
  int* partial   = counts + N_NODES;                 // N
  int* blocksum  = partial + N_NODES;                // 128
  int* blockoff  = blocksum + 128;                   // 128
  int* cursor    = blockoff + 128;                   // N
  int4* rec      = (int4*)(cursor + N_NODES);        // E x 16B

  hipLaunchKernelGGL(init_kernel, dim3((N_NODES + 255) / 256), dim3(256), 0,
                     stream, deg_in, deg_out, counts, cursor);
  hipLaunchKernelGGL(deg_kernel, dim3((N_EDGES / 2 + 255) / 256), dim3(256), 0,
                     stream, (const int4*)el, (const float2*)ew, deg_in,
                     deg_out, counts);
  hipLaunchKernelGGL(scan1_kernel, dim3(N_CHUNKS), dim3(256), 0, stream,
                     counts, partial, blocksum);
  hipLaunchKernelGGL(scan2_kernel, dim3(1), dim3(128), 0, stream, blocksum,
                     blockoff);
  hipLaunchKernelGGL(fill_kernel, dim3((N_EDGES + 255) / 256), dim3(256), 0,
                     stream, el, ew, deg_in, deg_out, partial, blockoff, cursor,
                     rec);
  hipLaunchKernelGGL(gather_kernel, dim3((N_NODES + 3) / 4), dim3(256), 0,
                     stream, x, ef, partial, blockoff, counts, rec, acc, g,
                     wsum);
  hipLaunchKernelGGL(final_kernel, dim3((N_NODES + 63) / 64), dim3(256), 0,
                     stream, x, deg_in, deg_out, wsum, g, W_lin, b_lin, W_edge,
                     b_edge, acc);
}

// Round 4
// 535.371 us; speedup vs baseline: 2.8529x; 1.1832x over previous
//
#include <hip/hip_runtime.h>

#define N_NODES 100000
#define N_EDGES 1600000
#define D 128
#define DE 32
#define SCAN_CHUNK 1024
#define N_CHUNKS ((N_NODES + SCAN_CHUNK - 1) / SCAN_CHUNK)  // 98

// NOTE on eps: reference divides by sqrt(deg_in*deg_out)+1e-10 with both
// degrees >= 1, so the +1e-10 is a 1e-10 relative perturbation — far below
// f32 rounding. We factor w = ew * rsqrt(di) * rsqrt(do).

// ---------------------------------------------------------------------------
// K1: zero deg replicas + cursor (contiguous 5N region).
__global__ __launch_bounds__(256) void init_kernel(int* __restrict__ z) {
  int idx = blockIdx.x * 256 + threadIdx.x;
  if (idx < 5 * N_NODES) z[idx] = 0;
}

// ---------------------------------------------------------------------------
// K2: per-edge: deg_in replica atomic + cursor position atomic. 2 edges/thr.
__global__ __launch_bounds__(256) void pos_kernel(
    const int4* __restrict__ el2, const float2* __restrict__ ew2,
    float* __restrict__ deg4, int* __restrict__ cursor,
    int2* __restrict__ pos2) {
  int i = blockIdx.x * 256 + threadIdx.x;  // edge-pair index
  if (i >= N_EDGES / 2) return;
  int4 e = el2[i];
  float2 w = ew2[i];
  int r = (threadIdx.x & 3) * N_NODES;
  atomicAdd(&deg4[r + e.x], w.x);
  atomicAdd(&deg4[r + e.z], w.y);
  int2 p;
  p.x = atomicAdd(&cursor[e.y], 1);
  p.y = atomicAdd(&cursor[e.w], 1);
  pos2[i] = p;
}

// ---------------------------------------------------------------------------
// K3a: per-1024-chunk exclusive scan of counts(=cursor) -> partial, totals;
// also folds the deg replica reduction into rdi = rsqrt(1 + sum).
__global__ __launch_bounds__(256) void scan1_kernel(
    const int* __restrict__ counts, const float* __restrict__ deg4,
    int* __restrict__ partial, int* __restrict__ blocksum,
    float* __restrict__ rdi) {
  __shared__ int lds[256];
  int t = threadIdx.x;
  int base = blockIdx.x * SCAN_CHUNK + t * 4;
  int c[4];
  int s = 0;
#pragma unroll
  for (int k = 0; k < 4; k++) {
    c[k] = (base + k < N_NODES) ? counts[base + k] : 0;
    s += c[k];
  }
  lds[t] = s;
  __syncthreads();
  for (int off = 1; off < 256; off <<= 1) {
    int tmp = (t >= off) ? lds[t - off] : 0;
    __syncthreads();
    lds[t] += tmp;
    __syncthreads();
  }
  int run = lds[t] - s;
#pragma unroll
  for (int k = 0; k < 4; k++) {
    int v = base + k;
    if (v < N_NODES) {
      partial[v] = run;
      rdi[v] = rsqrtf(1.f + deg4[v] + deg4[N_NODES + v] +
                      deg4[2 * N_NODES + v] + deg4[3 * N_NODES + v]);
    }
    run += c[k];
  }
  if (t == 255) blocksum[blockIdx.x] = lds[255];
}

// ---------------------------------------------------------------------------
// K3b: exclusive scan of the 98 chunk totals.
__global__ __launch_bounds__(128) void scan2_kernel(
    const int* __restrict__ blocksum, int* __restrict__ blockoff) {
  __shared__ int lds[128];
  int t = threadIdx.x;
  int v = (t < N_CHUNKS) ? blocksum[t] : 0;
  lds[t] = v;
  __syncthreads();
  for (int off = 1; off < 128; off <<= 1) {
    int tmp = (t >= off) ? lds[t - off] : 0;
    __syncthreads();
    lds[t] += tmp;
    __syncthreads();
  }
  if (t < N_CHUNKS) blockoff[t] = lds[t] - v;
}

// ---------------------------------------------------------------------------
// K4: place 16B AoS records {src, eid, ew, 0} at start[dst]+pos. No atomics.
__global__ __launch_bounds__(256) void place_kernel(
    const int4* __restrict__ el2, const float2* __restrict__ ew2,
    const int2* __restrict__ pos2, const int* __restrict__ partial,
    const int* __restrict__ blockoff, int4* __restrict__ rec) {
  int i = blockIdx.x * 256 + threadIdx.x;  // edge-pair index
  if (i >= N_EDGES / 2) return;
  int4 e = el2[i];
  float2 w = ew2[i];
  int2 p = pos2[i];
  int4 rA, rB;
  rA.x = e.x; rA.y = 2 * i;     rA.z = __float_as_int(w.x); rA.w = 0;
  rB.x = e.z; rB.y = 2 * i + 1; rB.z = __float_as_int(w.y); rB.w = 0;
  rec[partial[e.y] + blockoff[e.y >> 10] + p.x] = rA;
  rec[partial[e.w] + blockoff[e.w >> 10] + p.y] = rB;
}

// ---------------------------------------------------------------------------
// K5: one wave per dst node.
//  pass1: dsum = sum raw ew  -> rdo = rsqrt(1+dsum)   (replaces deg_out atomics)
//  pass2: per-lane w = ew*rdi[src]*rdo; shfl-broadcast; accumulate
//         sum(w*x[src]), sum(w*ef), sum(w). Plain stores, no atomics.
__global__ __launch_bounds__(256) void gather_kernel(
    const float* __restrict__ x, const float* __restrict__ ef,
    const int* __restrict__ partial, const int* __restrict__ blockoff,
    const int* __restrict__ counts, const int4* __restrict__ rec,
    const float* __restrict__ rdi, float* __restrict__ acc,
    float* __restrict__ g, float* __restrict__ wsum,
    float* __restrict__ rdo_arr) {
  int wid = threadIdx.x >> 6;
  int lane = threadIdx.x & 63;
  int v = blockIdx.x * 4 + wid;
  if (v >= N_NODES) return;
  int start = partial[v] + blockoff[v >> 10];
  int cnt = counts[v];

  // pass 1: raw weighted in-degree of v
  float dsum = 0.f;
  for (int p = lane; p < cnt; p += 64)
    dsum += __int_as_float(rec[start + p].z);
#pragma unroll
  for (int off = 32; off; off >>= 1) dsum += __shfl_xor(dsum, off);
  float rdo = rsqrtf(1.f + dsum);

  float a0 = 0.f, a1 = 0.f, b0 = 0.f, b1 = 0.f, ga = 0.f, wsv = 0.f;
  for (int base = 0; base < cnt; base += 64) {
    int nb = cnt - base;
    if (nb > 64) nb = 64;
    int s_l = 0, e_l = 0;
    float w_l = 0.f;
    if (lane < nb) {
      int4 r = rec[start + base + lane];
      s_l = r.x;
      e_l = r.y;
      w_l = __int_as_float(r.z) * rdi[r.x] * rdo;
      wsv += w_l;
    }
    int i = 0;
    for (; i + 2 <= nb; i += 2) {
      int sA = __shfl(s_l, i), sB = __shfl(s_l, i + 1);
      float wA = __shfl(w_l, i), wB = __shfl(w_l, i + 1);
      int eA = __shfl(e_l, i), eB = __shfl(e_l, i + 1);
      const float* xA = x + (size_t)sA * D;
      const float* xB = x + (size_t)sB * D;
      float xa0 = xA[lane], xa1 = xA[lane + 64];
      float xb0 = xB[lane], xb1 = xB[lane + 64];
      float we = (lane < 32) ? wA : wB;
      int ee = (lane < 32) ? eA : eB;
      float efv = ef[(size_t)ee * DE + (lane & 31)];
      a0 = fmaf(wA, xa0, a0);
      a1 = fmaf(wA, xa1, a1);
      b0 = fmaf(wB, xb0, b0);
      b1 = fmaf(wB, xb1, b1);
      ga = fmaf(we, efv, ga);
    }
    if (i < nb) {
      int sA = __shfl(s_l, i);
      float wA = __shfl(w_l, i);
      int eA = __shfl(e_l, i);
      const float* xA = x + (size_t)sA * D;
      a0 = fmaf(wA, xA[lane], a0);
      a1 = fmaf(wA, xA[lane + 64], a1);
      if (lane < DE) ga = fmaf(wA, ef[(size_t)eA * DE + lane], ga);
    }
  }
  a0 += b0;
  a1 += b1;
#pragma unroll
  for (int off = 32; off; off >>= 1) wsv += __shfl_xor(wsv, off);
  float gaHi = __shfl(ga, (lane + 32) & 63);
  float* ad = acc + (size_t)v * D;
  ad[lane] = a0;
  ad[lane + 64] = a1;
  if (lane < DE) g[v * DE + lane] = ga + gaHi;
  if (lane == 0) {
    wsum[v] = wsv;
    rdo_arr[v] = rdo;
  }
}

// ---------------------------------------------------------------------------
// K6: two-stage LDS GEMM per 64-node block (unchanged structure; wself=rdi*rdo).
__global__ __launch_bounds__(256) void final_kernel(
    const float* __restrict__ x, const float* __restrict__ rdi,
    const float* __restrict__ rdo_arr, const float* __restrict__ wsum,
    const float* __restrict__ g, const float* __restrict__ W_lin,
    const float* __restrict__ b_lin, const float* __restrict__ W_edge,
    const float* __restrict__ b_edge, float* __restrict__ acc) {
  __shared__ float upd[64][132];
  __shared__ float wtile[32][132];
  __shared__ float g_lds[64][36];
  __shared__ float wselfS[64], wsS[64];

  int t = threadIdx.x;
  int vbase = blockIdx.x * 64;
  int ti = t >> 3;
  int tj = t & 7;
  int swz = 4 * tj;

  for (int idx = t; idx < 64 * DE; idx += 256) {
    int n = idx >> 5, k = idx & 31;
    int v = vbase + n;
    g_lds[n][k] = (v < N_NODES) ? g[v * DE + k] : 0.f;
  }
  if (t < 64) {
    int v = vbase + t;
    if (v < N_NODES) {
      wselfS[t] = rdi[v] * rdo_arr[v];
      wsS[t] = wsum[v];
    } else {
      wselfS[t] = 0.f;
      wsS[t] = 0.f;
    }
  }

  int n0 = 2 * ti, n1 = n0 + 1;
  bool ok0 = (vbase + n0) < N_NODES;
  bool ok1 = (vbase + n1) < N_NODES;

  for (int dt = 0; dt < 4; ++dt) {
    __syncthreads();
    for (int idx = t; idx < 32 * DE; idx += 256) {
      int dd = idx >> 5, k = idx & 31;
      wtile[dd][k ^ (4 * (dd >> 2))] = W_edge[(dt * 32 + dd) * DE + k];
    }
    __syncthreads();
    int dcol = dt * 32 + 4 * tj;
    float4 be = *(const float4*)&b_edge[dcol];
    float4 o0 = make_float4(0.f, 0.f, 0.f, 0.f), o1 = o0;
    if (ok0) {
      float4 a = *(const float4*)&acc[(size_t)(vbase + n0) * D + dcol];
      float4 xv = *(const float4*)&x[(size_t)(vbase + n0) * D + dcol];
      float wf = wselfS[n0], ws = wsS[n0];
      o0.x = a.x + wf * xv.x + ws * be.x;
      o0.y = a.y + wf * xv.y + ws * be.y;
      o0.z = a.z + wf * xv.z + ws * be.z;
      o0.w = a.w + wf * xv.w + ws * be.w;
    }
    if (ok1) {
      float4 a = *(const float4*)&acc[(size_t)(vbase + n1) * D + dcol];
      float4 xv = *(const float4*)&x[(size_t)(vbase + n1) * D + dcol];
      float wf = wselfS[n1], ws = wsS[n1];
      o1.x = a.x + wf * xv.x + ws * be.x;
      o1.y = a.y + wf * xv.y + ws * be.y;
      o1.z = a.z + wf * xv.z + ws * be.z;
      o1.w = a.w + wf * xv.w + ws * be.w;
    }
#pragma unroll
    for (int k0 = 0; k0 < DE; k0 += 4) {
      float4 u0 = *(const float4*)&g_lds[n0][k0];
      float4 u1 = *(const float4*)&g_lds[n1][k0];
      float4 w0 = *(const float4*)&wtile[4 * tj + 0][k0 ^ swz];
      float4 w1 = *(const float4*)&wtile[4 * tj + 1][k0 ^ swz];
      float4 w2 = *(const float4*)&wtile[4 * tj + 2][k0 ^ swz];
      float4 w3 = *(const float4*)&wtile[4 * tj + 3][k0 ^ swz];
      o0.x += u0.x * w0.x + u0.y * w0.y + u0.z * w0.z + u0.w * w0.w;
      o0.y += u0.x * w1.x + u0.y * w1.y + u0.z * w1.z + u0.w * w1.w;
      o0.z += u0.x * w2.x + u0.y * w2.y + u0.z * w2.z + u0.w * w2.w;
      o0.w += u0.x * w3.x + u0.y * w3.y + u0.z * w3.z + u0.w * w3.w;
      o1.x += u1.x * w0.x + u1.y * w0.y + u1.z * w0.z + u1.w * w0.w;
      o1.y += u1.x * w1.x + u1.y * w1.y + u1.z * w1.z + u1.w * w1.w;
      o1.z += u1.x * w2.x + u1.y * w2.y + u1.z * w2.z + u1.w * w2.w;
      o1.w += u1.x * w3.x + u1.y * w3.y + u1.z * w3.z + u1.w * w3.w;
    }
    *(float4*)&upd[n0][dcol] = o0;
    *(float4*)&upd[n1][dcol] = o1;
  }

  for (int jt = 0; jt < 4; ++jt) {
    __syncthreads();
    for (int idx = t; idx < 32 * D; idx += 256) {
      int jj = idx >> 7, k = idx & 127;
      wtile[jj][k ^ (4 * (jj >> 2))] = W_lin[(jt * 32 + jj) * D + k];
    }
    __syncthreads();
    int jcol = jt * 32 + 4 * tj;
    float4 bl = *(const float4*)&b_lin[jcol];
    float4 o0 = bl, o1 = bl;
#pragma unroll 4
    for (int k0 = 0; k0 < D; k0 += 4) {
      float4 u0 = *(const float4*)&upd[n0][k0];
      float4 u1 = *(const float4*)&upd[n1][k0];
      float4 w0 = *(const float4*)&wtile[4 * tj + 0][k0 ^ swz];
      float4 w1 = *(const float4*)&wtile[4 * tj + 1][k0 ^ swz];
      float4 w2 = *(const float4*)&wtile[4 * tj + 2][k0 ^ swz];
      float4 w3 = *(const float4*)&wtile[4 * tj + 3][k0 ^ swz];
      o0.x += u0.x * w0.x + u0.y * w0.y + u0.z * w0.z + u0.w * w0.w;
      o0.y += u0.x * w1.x + u0.y * w1.y + u0.z * w1.z + u0.w * w1.w;
      o0.z += u0.x * w2.x + u0.y * w2.y + u0.z * w2.z + u0.w * w2.w;
      o0.w += u0.x * w3.x + u0.y * w3.y + u0.z * w3.z + u0.w * w3.w;
      o1.x += u1.x * w0.x + u1.y * w0.y + u1.z * w0.z + u1.w * w0.w;
      o1.y += u1.x * w1.x + u1.y * w1.y + u1.z * w1.z + u1.w * w1.w;
      o1.z += u1.x * w2.x + u1.y * w2.y + u1.z * w2.z + u1.w * w2.w;
      o1.w += u1.x * w3.x + u1.y * w3.y + u1.z * w3.z + u1.w * w3.w;
    }
    o0.x = fmaxf(o0.x, 0.f); o0.y = fmaxf(o0.y, 0.f);
    o0.z = fmaxf(o0.z, 0.f); o0.w = fmaxf(o0.w, 0.f);
    o1.x = fmaxf(o1.x, 0.f); o1.y = fmaxf(o1.y, 0.f);
    o1.z = fmaxf(o1.z, 0.f); o1.w = fmaxf(o1.w, 0.f);
    if (ok0) *(float4*)&acc[(size_t)(vbase + n0) * D + jcol] = o0;
    if (ok1) *(float4*)&acc[(size_t)(vbase + n1) * D + jcol] = o1;
  }
}

// ---------------------------------------------------------------------------
extern "C" void kernel_launch(void* const* d_in, const int* in_sizes, int n_in,
                              void* d_out, int out_size, void* d_ws,
                              size_t ws_size, hipStream_t stream) {
  const float* x      = (const float*)d_in[0];
  const int*   el     = (const int*)d_in[1];
  const float* ew     = (const float*)d_in[2];
  const float* ef     = (const float*)d_in[3];
  const float* W_lin  = (const float*)d_in[4];
  const float* b_lin  = (const float*)d_in[5];
  const float* W_edge = (const float*)d_in[6];
  const float* b_edge = (const float*)d_in[7];

  float* acc = (float*)d_out;

  // workspace layout (~48 MB), rec first for 16B alignment
  int4* rec      = (int4*)d_ws;                         // E x 16B
  int*  pos      = (int*)(rec + N_EDGES);               // E
  float* deg4    = (float*)(pos + N_EDGES);             // 4N  (zeroed w/ cursor)
  int*  cursor   = (int*)(deg4 + 4 * N_NODES);          // N   (== counts after K2)
  int*  partial  = cursor + N_NODES;                    // N
  int*  blocksum = partial + N_NODES;                   // 128
  int*  blockoff = blocksum + 128;                      // 128
  float* rdi     = (float*)(blockoff + 128);            // N
  float* rdo     = rdi + N_NODES;                       // N
  float* wsum    = rdo + N_NODES;                       // N
  float* g       = wsum + N_NODES;                      // N*32

  hipLaunchKernelGGL(init_kernel, dim3((5 * N_NODES + 255) / 256), dim3(256),
                     0, stream, (int*)deg4);
  hipLaunchKernelGGL(pos_kernel, dim3((N_EDGES / 2 + 255) / 256), dim3(256), 0,
                     stream, (const int4*)el, (const float2*)ew, deg4, cursor,
                     (int2*)pos);
  hipLaunchKernelGGL(scan1_kernel, dim3(N_CHUNKS), dim3(256), 0, stream,
                     cursor, deg4, partial, blocksum, rdi);
  hipLaunchKernelGGL(scan2_kernel, dim3(1), dim3(128), 0, stream, blocksum,
                     blockoff);
  hipLaunchKernelGGL(place_kernel, dim3((N_EDGES / 2 + 255) / 256), dim3(256),
                     0, stream, (const int4*)el, (const float2*)ew,
                     (const int2*)pos, partial, blockoff, rec);
  hipLaunchKernelGGL(gather_kernel, dim3((N_NODES + 3) / 4), dim3(256), 0,
                     stream, x, ef, partial, blockoff, cursor, rec, rdi, acc, g,
                     wsum, rdo);
  hipLaunchKernelGGL(final_kernel, dim3((N_NODES + 63) / 64), dim3(256), 0,
                     stream, x, rdi, rdo, wsum, g, W_lin, b_lin, W_edge,
                     b_edge, acc);
}